// Round 12
// baseline (260.848 us; speedup 1.0000x reference)
//
#include <hip/hip_runtime.h>

// x: (64, 8192, 256) float32, cumsum along dim 1.
#define BATCH 64
#define LEN   8192
#define DIM   256
#define D4    (DIM / 4)        // 64 float4 per row
#define Q     2                // channel slices per batch: 512 B per slice-row
#define SF4   (D4 / Q)         // 32 float4 per slice
#define NTHR  1024
#define R     4                // rows per thread per tile
#define GROUPS (NTHR / SF4)    // 32 row-groups per tile
#define TILE  (GROUPS * R)     // 128 rows per tile
#define NT    (LEN / TILE)     // 64 tiles, serial per block (carry in regs)
#define NWAVES (NTHR / 64)     // 16
#define LGW   (64 / SF4)       // 2 local groups per wave

__device__ __forceinline__ void f4_add(float4& a, const float4& v) {
    a.x += v.x; a.y += v.y; a.z += v.z; a.w += v.w;
}

// ROUND 12 discriminator: 128 blocks x 1024 threads (half the CUs, same total
// waves, 512 B contiguous runs per 32-lane group). If the ~4.8 TB/s plateau is
// a GLOBAL memory-system limit, this ties; if per-CU, it regresses ~2x.
__global__ __launch_bounds__(NTHR, 1) void chained_scan_kernel(
    const float* __restrict__ x, float* __restrict__ out)
{
    __shared__ float4 wtot[2][NWAVES][SF4];   // 16 KiB, parity double-buffered

    const int q    = blockIdx.x;         // channel slice (0..1)
    const int b    = blockIdx.y;         // batch
    const int t    = threadIdx.x;        // 0..1023
    const int f    = t & (SF4 - 1);      // f4 within slice (0..31)
    const int g    = t >> 5;             // group within tile (0..31), 4 rows each
    const int lane = t & 63;
    const int w    = t >> 6;             // wave 0..15
    const int lg   = lane >> 5;          // local group within wave (0..1)

    const size_t chain = (size_t)b * LEN * D4 + (size_t)q * SF4 + f;
    const float4* xp = reinterpret_cast<const float4*>(x) + chain;
    float4*       op = reinterpret_cast<float4*>(out) + chain;
    const size_t r0 = (size_t)(g * R) * D4;  // thread's first row offset in a tile

    float4 carry = make_float4(0.f, 0.f, 0.f, 0.f);

    // Prefetch tile 0.
    float4 a[R];
#pragma unroll
    for (int r = 0; r < R; ++r) a[r] = xp[r0 + (size_t)r * D4];

    float4 held[R];                      // deferred output rows of previous tile
    size_t held_ob = 0;

    for (int tile = 0; tile < NT; ++tile) {
        // 1) Issue next tile's loads.
        const int nxt = (tile + 1 < NT) ? tile + 1 : tile;
        const size_t nb = (size_t)nxt * TILE * D4 + r0;
        float4 nx[R];
#pragma unroll
        for (int r = 0; r < R; ++r) nx[r] = xp[nb + (size_t)r * D4];

        // 2) Flush previous tile's outputs (overlaps with the loads above).
        if (tile > 0) {
#pragma unroll
            for (int r = 0; r < R; ++r)
                op[held_ob + (size_t)r * D4] = held[r];
        }

        // 3) 4-row group sum.
        float4 ls = a[0];
#pragma unroll
        for (int r = 1; r < R; ++r) f4_add(ls, a[r]);

        // Wave-inclusive scan over the 2 local groups (same-f lanes, stride 32).
        float4 incl = ls;
        {
            float4 o;
            o.x = __shfl_up(incl.x, SF4, 64);
            o.y = __shfl_up(incl.y, SF4, 64);
            o.z = __shfl_up(incl.z, SF4, 64);
            o.w = __shfl_up(incl.w, SF4, 64);
            if (lg >= 1) f4_add(incl, o);
        }

        // Publish per-wave totals (lanes 32..63 hold them), parity-buffered.
        const int par = tile & 1;
        if (lane >= 32) wtot[par][w][f] = incl;
        __syncthreads();

        // Cross-wave exclusive prefix + tile total (16 broadcast reads).
        float4 cross = make_float4(0.f, 0.f, 0.f, 0.f);
        float4 tot   = make_float4(0.f, 0.f, 0.f, 0.f);
#pragma unroll
        for (int ww = 0; ww < NWAVES; ++ww) {
            float4 s = wtot[par][ww][f];
            if (ww < w) f4_add(cross, s);
            f4_add(tot, s);
        }

        // acc = carry + exclusive-prefix-of-this-group = carry + cross + incl - ls
        float4 acc = carry;
        f4_add(acc, cross);
        f4_add(acc, incl);
        acc.x -= ls.x; acc.y -= ls.y; acc.z -= ls.z; acc.w -= ls.w;

        // 4) Produce this tile's outputs into held registers (store next iter).
#pragma unroll
        for (int r = 0; r < R; ++r) {
            f4_add(acc, a[r]);
            held[r] = acc;
        }
        held_ob = (size_t)tile * TILE * D4 + r0;

        f4_add(carry, tot);
#pragma unroll
        for (int r = 0; r < R; ++r) a[r] = nx[r];
    }

    // Flush the final tile's outputs.
#pragma unroll
    for (int r = 0; r < R; ++r)
        op[held_ob + (size_t)r * D4] = held[r];
}

extern "C" void kernel_launch(void* const* d_in, const int* in_sizes, int n_in,
                              void* d_out, int out_size, void* d_ws, size_t ws_size,
                              hipStream_t stream) {
    const float* x = (const float*)d_in[0];
    float* out = (float*)d_out;
    chained_scan_kernel<<<dim3(Q, BATCH), NTHR, 0, stream>>>(x, out);
}